// Round 1
// 124.819 us; speedup vs baseline: 1.1117x; 1.1117x over previous
//
#include <hip/hip_runtime.h>
#include <math.h>

#define B_ 4
#define L_ 4096
#define D_ 256
#define A_ 64
#define M_ (B_*L_)   // 16384 flat rows

typedef _Float16 half4 __attribute__((ext_vector_type(4)));
typedef _Float16 half8 __attribute__((ext_vector_type(8)));
typedef __attribute__((ext_vector_type(4))) float floatx4;

__device__ __forceinline__ unsigned short f2h_(float f) {
    _Float16 h = (_Float16)f;
    return __builtin_bit_cast(unsigned short, h);
}

// ---------------------------------------------------------------------------
// wconv: W f32 [256][64] -> W^T fp16 [64][256]. Wq scaled by 1/ln2 (exp2
// softmax domain). grid (3), block 256.
// ---------------------------------------------------------------------------
__global__ __launch_bounds__(256) void wconv_kernel(
    const float* __restrict__ Wq, const float* __restrict__ Wk,
    const float* __restrict__ Wv, unsigned short* __restrict__ wt)
{
    const int w = blockIdx.x, t = threadIdx.x;
    const float* W = (w == 0) ? Wq : (w == 1) ? Wk : Wv;
    unsigned short* o = wt + w * A_ * D_;
    const float scale = (w == 0) ? 1.44269504f : 1.0f;
    __shared__ float T[A_ * 260];
    #pragma unroll
    for (int p = 0; p < 16; ++p) {
        int idx = p * 256 + t;
        int d = idx >> 4, a4 = (idx & 15) * 4;
        float4 v = *(const float4*)(W + d * A_ + a4);
        T[(a4 + 0) * 260 + d] = v.x * scale;
        T[(a4 + 1) * 260 + d] = v.y * scale;
        T[(a4 + 2) * 260 + d] = v.z * scale;
        T[(a4 + 3) * 260 + d] = v.w * scale;
    }
    __syncthreads();
    const int a = t >> 2, d0 = (t & 3) * 64;
    #pragma unroll
    for (int i = 0; i < 16; ++i) {
        float4 v = *(const float4*)(&T[a * 260 + d0 + 4 * i]);
        ushort4 s;
        s.x = f2h_(v.x); s.y = f2h_(v.y); s.z = f2h_(v.z); s.w = f2h_(v.w);
        *(ushort4*)(o + a * D_ + d0 + 4 * i) = s;
    }
}

// ---------------------------------------------------------------------------
// proj: one block per 32 x-rows computes ALL 3 projections (x staged once).
// grid (M/32), block 384 = 6 waves: wave = (w = wid>>1, mt = wid&1).
// Each wave: 16 rows x 64 cols, 32 MFMA. Wave-local epilogue via LDS.
// q/k fp16 [M][64]; v fp16 TRANSPOSED [B][64][L].
// ---------------------------------------------------------------------------
__global__ __launch_bounds__(384) void proj_kernel(
    const float* __restrict__ x,           // [M][256] f32
    const unsigned short* __restrict__ wt, // [3][64][256] fp16 (W^T)
    unsigned short* __restrict__ qo,
    unsigned short* __restrict__ ko,
    unsigned short* __restrict__ vto)
{
    __shared__ __align__(16) unsigned short Xh[32 * 264];   // 16.5 KB
    __shared__ __align__(16) unsigned short Cst[6 * 1536];  // 18 KB
    const int t = threadIdx.x, m0 = blockIdx.x * 32;

    // stage x tile 32x256 -> fp16 (2048 float4 over 384 threads)
    #pragma unroll
    for (int p = 0; p < 6; ++p) {
        int idx = p * 384 + t;
        if (idx < 2048) {
            int row = idx >> 6, col = (idx & 63) * 4;
            float4 v = *(const float4*)(x + (size_t)(m0 + row) * D_ + col);
            ushort4 s;
            s.x = f2h_(v.x); s.y = f2h_(v.y); s.z = f2h_(v.z); s.w = f2h_(v.w);
            *(ushort4*)(Xh + row * 264 + col) = s;
        }
    }
    __syncthreads();

    const int wid = t >> 6, lane = t & 63, c = lane & 15, g = lane >> 4;
    const int w = wid >> 1, mt = wid & 1;

    half8 xa[8];
    #pragma unroll
    for (int s = 0; s < 8; ++s)
        xa[s] = *(const half8*)(Xh + (16 * mt + c) * 264 + 32 * s + 8 * g);

    const unsigned short* wsrc = wt + w * A_ * D_;
    unsigned short* Cw = Cst + wid * 1536;
    #pragma unroll
    for (int nt = 0; nt < 4; ++nt) {
        floatx4 acc = {0.f, 0.f, 0.f, 0.f};
        #pragma unroll
        for (int s = 0; s < 8; ++s) {
            half8 wb = *(const half8*)(wsrc + (16 * nt + c) * D_ + 32 * s + 8 * g);
            acc = __builtin_amdgcn_mfma_f32_16x16x32_f16(xa[s], wb, acc, 0, 0, 0);
        }
        // C[m=4g+r][a=16nt+c]
        if (w < 2) {
            #pragma unroll
            for (int r = 0; r < 4; ++r)
                Cw[(4 * g + r) * 72 + 16 * nt + c] = f2h_(acc[r]);      // [m16][72]
        } else {
            #pragma unroll
            for (int r = 0; r < 4; ++r)
                Cw[(16 * nt + c) * 24 + 4 * g + r] = f2h_(acc[r]);      // [a64][24]
        }
    }

    // q/k: wave-local store (wave reads only its own Cst region)
    if (w < 2) {
        unsigned short* o = (w == 0) ? qo : ko;
        const int row16 = lane >> 2, seg = lane & 3;
        uint4 d0 = *(const uint4*)(Cw + row16 * 72 + seg * 16);
        uint4 d1 = *(const uint4*)(Cw + row16 * 72 + seg * 16 + 8);
        unsigned short* p = o + (size_t)(m0 + 16 * mt + row16) * A_ + seg * 16;
        *(uint4*)(p) = d0;
        *(uint4*)(p + 8) = d1;
    }
    __syncthreads();
    // v: combined store from both w=2 waves -> 64B contiguous per a-row
    if (t < 256) {
        const int a = t >> 2, quarter = t & 3;
        const int o = quarter * 8, mtv = o >> 4, idx = o & 15;
        uint4 d = *(const uint4*)(Cst + (4 + mtv) * 1536 + a * 24 + idx);
        const int bb = m0 >> 12, l0 = m0 & (L_ - 1);
        *(uint4*)(vto + ((size_t)(bb * A_ + a)) * L_ + l0 + o) = d;
    }
}

// ---------------------------------------------------------------------------
// attn: split-K flash, 64-query blocks. grid (512) 1D, block 512 = 8 waves.
// Balanced mapping: slot = bx&255 is dispatched to the same CU in both
// rounds (256 blocks/round over 256 CUs); round 0 gets (b0, qt0), round 1
// gets (b0+2, 63-qt0) -> per-CU key-tile total is constant (~32.5) since
// T(q)+T(63-q) = 65. All 512 blocks co-resident (36 KB LDS -> 4 blk/CU cap).
// Wave = (qsub = wid>>1 in 0..3, ph = wid&1): 16 q-rows x one 64-key tile.
// Each staged K/V tile now serves 64 queries (2x reuse vs 32-q blocks):
// staging traffic 266 MB -> 133 MB, barriers per tile halved.
// S^T form: QK^T A=K,B=Q -> S^T[key][q=c]; softmax per-lane q row (exp2);
// PV: A=V^T 8B LDS frags, B=P^T in registers (K=16 chain).
// Emits UNNORMALIZED partial (O,m,l): h=0 -> out, h=1 -> po1/ml1.
// ---------------------------------------------------------------------------
__global__ __launch_bounds__(512) void attn_kernel(
    const unsigned short* __restrict__ qb,  // [B][L][64] fp16 (x 1/ln2)
    const unsigned short* __restrict__ kb,  // [B][L][64] fp16
    const unsigned short* __restrict__ vt,  // [B][64][L] fp16
    float* __restrict__ out,                // partial O for h=0
    float* __restrict__ po1,                // partial O for h=1
    float2* __restrict__ ml0,               // (m,l) h=0  [B*L]
    float2* __restrict__ ml1)               // (m,l) h=1  [B*L]
{
    __shared__ __align__(16) unsigned short smem[4 * 4608];  // 36 KB
    unsigned short* Ks = smem;
    unsigned short* Vs = smem + 2 * 4608;

    const int t    = threadIdx.x;
    const int lane = t & 63;
    const int wid  = t >> 6;          // 0..7
    const int qsub = wid >> 1;        // 0..3
    const int ph   = wid & 1;
    const int c    = lane & 15;
    const int g    = lane >> 4;

    // balanced (b, qt, h) from 1D block id
    const int bx   = blockIdx.x;
    const int slot = bx & 255, rr = bx >> 8;
    const int qt0  = slot >> 2;
    const int h    = slot & 1;
    const int b    = ((slot >> 1) & 1) + 2 * rr;
    const int qt   = rr ? (63 - qt0) : qt0;

    const int q0    = qt * 64;
    const int qrow0 = q0 + 16 * qsub;
    const int qme   = qrow0 + c;

    const size_t base  = (size_t)b * L_ * A_;
    const size_t vbase = (size_t)b * A_ * L_;

    half8 qf[2];
    {
        const unsigned short* qp = qb + base + (size_t)(qrow0 + c) * A_ + g * 8;
        qf[0] = *(const half8*)(qp);
        qf[1] = *(const half8*)(qp + 32);
    }

    floatx4 O4[4];          // O^T[a=16at+4g+r][q=c], unnormalized
    #pragma unroll
    for (int at = 0; at < 4; ++at) O4[at] = (floatx4){0.f, 0.f, 0.f, 0.f};
    float m_ = -INFINITY, l_ = 0.f;

    const int T   = qt + 1;           // 64-key tiles covering [0, q0+64)
    const int Th  = (T + 1) >> 1;
    const int t0  = h ? Th : 0;
    const int t1  = h ? T : Th;
    const int nIt = (t1 - t0 + 1) >> 1;
    const int Tm1 = T - 1;

    for (int it = 0; it < nIt; ++it) {
        __syncthreads();
        #pragma unroll
        for (int tile = 0; tile < 2; ++tile) {
            const int kts = t0 + 2 * it + tile;
            if (kts < t1) {
                const int k0s = kts << 6;
                const int row = t >> 3, c8 = t & 7;   // 512 threads cover tile
                uint4 dK = *(const uint4*)(kb + base + (size_t)k0s * 64 + t * 8);
                *(uint4*)(Ks + tile * 4608 + row * 72 + c8 * 8) = dK;
                uint4 dV = *(const uint4*)(vt + vbase + (size_t)row * L_ + k0s + c8 * 8);
                *(uint4*)(Vs + tile * 4608 + row * 72 + c8 * 8) = dV;
            }
        }
        __syncthreads();

        const int kt = t0 + 2 * it + ph;
        if (kt >= t1) continue;          // loop-top barriers stay convergent
        const int k0 = kt << 6;
        const unsigned short* Kw = Ks + ph * 4608;
        const unsigned short* Vw = Vs + ph * 4608;

        // ---- S^T = K . Q^T ----
        floatx4 S4[4];
        #pragma unroll
        for (int nt = 0; nt < 4; ++nt) S4[nt] = (floatx4){0.f, 0.f, 0.f, 0.f};
        #pragma unroll
        for (int s = 0; s < 2; ++s)
            #pragma unroll
            for (int nt = 0; nt < 4; ++nt) {
                half8 kf = *(const half8*)(Kw + (16 * nt + c) * 72 + 32 * s + 8 * g);
                S4[nt] = __builtin_amdgcn_mfma_f32_16x16x32_f16(kf, qf[s], S4[nt], 0, 0, 0);
            }

        // ---- causal mask: only global tile T-1 straddles the diagonal ----
        if (kt == Tm1) {
            #pragma unroll
            for (int nt = 0; nt < 4; ++nt)
                #pragma unroll
                for (int r = 0; r < 4; ++r)
                    if (k0 + 16 * nt + 4 * g + r > qme) S4[nt][r] = -INFINITY;
        }

        // ---- online softmax (exp2 domain; per-lane q row) ----
        float tm = fmaxf(fmaxf(fmaxf(S4[0][0], S4[0][1]), fmaxf(S4[0][2], S4[0][3])),
                         fmaxf(fmaxf(S4[1][0], S4[1][1]), fmaxf(S4[1][2], S4[1][3])));
        tm = fmaxf(tm, fmaxf(fmaxf(fmaxf(S4[2][0], S4[2][1]), fmaxf(S4[2][2], S4[2][3])),
                             fmaxf(fmaxf(S4[3][0], S4[3][1]), fmaxf(S4[3][2], S4[3][3]))));
        tm = fmaxf(tm, __shfl_xor(tm, 16));
        tm = fmaxf(tm, __shfl_xor(tm, 32));
        const float mn  = fmaxf(m_, tm);
        const float mnc = fmaxf(mn, -3.0e38f);         // guard -inf - -inf
        const float al  = exp2f(fminf(m_ - mnc, 0.f)); // m_=-inf -> 0
        float rs = 0.f;
        half4 pf[4];
        #pragma unroll
        for (int nt = 0; nt < 4; ++nt) {
            #pragma unroll
            for (int r = 0; r < 4; ++r) {
                float p = exp2f(S4[nt][r] - mnc);      // masked: exp2(-inf)=0
                S4[nt][r] = p;
                rs += p;
            }
            pf[nt][0] = (_Float16)S4[nt][0];
            pf[nt][1] = (_Float16)S4[nt][1];
            pf[nt][2] = (_Float16)S4[nt][2];
            pf[nt][3] = (_Float16)S4[nt][3];
        }
        rs += __shfl_xor(rs, 16);
        rs += __shfl_xor(rs, 32);
        l_ = l_ * al + rs;
        m_ = mn;

        // ---- O^T = O^T*al + V^T . P^T  (V A-frags: 8B LDS reads) ----
        #pragma unroll
        for (int at = 0; at < 4; ++at) {
            O4[at] *= al;
            #pragma unroll
            for (int nt = 0; nt < 4; ++nt) {
                half4 va = *(const half4*)(Vw + (16 * at + c) * 72 + 16 * nt + 4 * g);
                O4[at] = __builtin_amdgcn_mfma_f32_16x16x16f16(va, pf[nt], O4[at], 0, 0, 0);
            }
        }
    }

    // ---- combine 2 phases per qsub; write unnormalized partial ----
    __syncthreads();
    float*  Of  = (float*)smem;                 // [wid][at][lane][r]  32 KB
    float2* mlb = (float2*)(smem + 16384);      // [wid][c]  (byte off 32768)
    #pragma unroll
    for (int at = 0; at < 4; ++at) {
        float4 v; v.x = O4[at][0]; v.y = O4[at][1]; v.z = O4[at][2]; v.w = O4[at][3];
        ((float4*)Of)[wid * 256 + at * 64 + lane] = v;
    }
    if (g == 0) { float2 ml; ml.x = m_; ml.y = l_; mlb[wid * 16 + c] = ml; }
    __syncthreads();

    {
        const int q64 = t >> 3, seg = t & 7;    // 64 q-rows x 8 segs
        const int qs = q64 >> 4, cc = q64 & 15;
        const float2 A0 = mlb[(2 * qs) * 16 + cc];
        const float2 A1 = mlb[(2 * qs + 1) * 16 + cc];
        const float mf = fmaxf(A0.x, A1.x);
        const float mc = fmaxf(mf, -3.0e38f);
        const float w0 = exp2f(A0.x - mc);      // -inf -> 0
        const float w1 = exp2f(A1.x - mc);
        const float ls = w0 * A0.y + w1 * A1.y;
        float res[8];
        #pragma unroll
        for (int u = 0; u < 8; ++u) {
            const int a = seg * 8 + u;
            const int at = a >> 4, gg = (a >> 2) & 3, r = a & 3;
            const int i0 = ((2 * qs) * 256 + at * 64 + gg * 16 + cc) * 4 + r;
            const int i1 = ((2 * qs + 1) * 256 + at * 64 + gg * 16 + cc) * 4 + r;
            res[u] = w0 * Of[i0] + w1 * Of[i1];
        }
        float* PO = h ? po1 : out;
        float* p = PO + (base + (size_t)(q0 + q64) * A_) + seg * 8;
        *(float4*)(p)     = make_float4(res[0], res[1], res[2], res[3]);
        *(float4*)(p + 4) = make_float4(res[4], res[5], res[6], res[7]);
        if (seg == 0) {
            float2 ml; ml.x = mf; ml.y = ls;
            (h ? ml1 : ml0)[b * L_ + q0 + q64] = ml;
        }
    }
}

// ---------------------------------------------------------------------------
// merge: final = (O0*w0 + O1*w1) / (l0*w0 + l1*w1). grid (1024), block 256.
// ---------------------------------------------------------------------------
__global__ __launch_bounds__(256) void merge_kernel(
    float* __restrict__ out, const float* __restrict__ po1,
    const float2* __restrict__ ml0, const float2* __restrict__ ml1)
{
    const int tg = blockIdx.x * 256 + threadIdx.x;   // 262144 float4s
    const int q = tg >> 4;
    const float2 a0 = ml0[q], a1 = ml1[q];
    const float mf = fmaxf(a0.x, a1.x);
    const float mc = fmaxf(mf, -3.0e38f);
    const float w0 = exp2f(a0.x - mc);
    const float w1 = exp2f(a1.x - mc);
    const float inv = 1.f / (w0 * a0.y + w1 * a1.y);
    float4 o0 = ((const float4*)out)[tg];
    float4 o1 = ((const float4*)po1)[tg];
    float4 r;
    r.x = (o0.x * w0 + o1.x * w1) * inv;
    r.y = (o0.y * w0 + o1.y * w1) * inv;
    r.z = (o0.z * w0 + o1.z * w1) * inv;
    r.w = (o0.w * w0 + o1.w * w1) * inv;
    ((float4*)out)[tg] = r;
}

// ---------------------------------------------------------------------------
extern "C" void kernel_launch(void* const* d_in, const int* in_sizes, int n_in,
                              void* d_out, int out_size, void* d_ws, size_t ws_size,
                              hipStream_t stream) {
    const float* x  = (const float*)d_in[0];
    const float* Wq = (const float*)d_in[1];
    const float* Wk = (const float*)d_in[2];
    const float* Wv = (const float*)d_in[3];

    char* ws = (char*)d_ws;
    unsigned short* qb = (unsigned short*)(ws);                    // 2 MB
    unsigned short* kb = (unsigned short*)(ws + (2u << 20));       // 2 MB
    unsigned short* vt = (unsigned short*)(ws + (4u << 20));       // 2 MB
    unsigned short* wt = (unsigned short*)(ws + (6u << 20));       // 96 KB
    float*  po1 = (float*) (ws + (6u << 20) + 98304);              // 4 MB
    float2* ml0 = (float2*)(ws + (6u << 20) + 98304 + (4u << 20));           // 128 KB
    float2* ml1 = (float2*)(ws + (6u << 20) + 98304 + (4u << 20) + 131072);  // 128 KB
    float* out = (float*)d_out;

    hipLaunchKernelGGL(wconv_kernel, dim3(3), dim3(256), 0, stream, Wq, Wk, Wv, wt);
    hipLaunchKernelGGL(proj_kernel, dim3(M_ / 32), dim3(384), 0, stream, x, wt, qb, kb, vt);
    hipLaunchKernelGGL(attn_kernel, dim3(512), dim3(512), 0, stream,
                       qb, kb, vt, out, po1, ml0, ml1);
    hipLaunchKernelGGL(merge_kernel, dim3(1024), dim3(256), 0, stream, out, po1, ml0, ml1);
}

// Round 2
// 123.564 us; speedup vs baseline: 1.1230x; 1.0102x over previous
//
#include <hip/hip_runtime.h>
#include <math.h>

#define B_ 4
#define L_ 4096
#define D_ 256
#define A_ 64
#define M_ (B_*L_)   // 16384 flat rows

typedef _Float16 half4 __attribute__((ext_vector_type(4)));
typedef _Float16 half8 __attribute__((ext_vector_type(8)));
typedef __attribute__((ext_vector_type(4))) float floatx4;

__device__ __forceinline__ unsigned short f2h_(float f) {
    _Float16 h = (_Float16)f;
    return __builtin_bit_cast(unsigned short, h);
}

// ---------------------------------------------------------------------------
// wconv: W f32 [256][64] -> W^T fp16 [64][256]. Wq scaled by 1/ln2 (exp2
// softmax domain). grid (3), block 256.
// ---------------------------------------------------------------------------
__global__ __launch_bounds__(256) void wconv_kernel(
    const float* __restrict__ Wq, const float* __restrict__ Wk,
    const float* __restrict__ Wv, unsigned short* __restrict__ wt)
{
    const int w = blockIdx.x, t = threadIdx.x;
    const float* W = (w == 0) ? Wq : (w == 1) ? Wk : Wv;
    unsigned short* o = wt + w * A_ * D_;
    const float scale = (w == 0) ? 1.44269504f : 1.0f;
    __shared__ float T[A_ * 260];
    #pragma unroll
    for (int p = 0; p < 16; ++p) {
        int idx = p * 256 + t;
        int d = idx >> 4, a4 = (idx & 15) * 4;
        float4 v = *(const float4*)(W + d * A_ + a4);
        T[(a4 + 0) * 260 + d] = v.x * scale;
        T[(a4 + 1) * 260 + d] = v.y * scale;
        T[(a4 + 2) * 260 + d] = v.z * scale;
        T[(a4 + 3) * 260 + d] = v.w * scale;
    }
    __syncthreads();
    const int a = t >> 2, d0 = (t & 3) * 64;
    #pragma unroll
    for (int i = 0; i < 16; ++i) {
        float4 v = *(const float4*)(&T[a * 260 + d0 + 4 * i]);
        ushort4 s;
        s.x = f2h_(v.x); s.y = f2h_(v.y); s.z = f2h_(v.z); s.w = f2h_(v.w);
        *(ushort4*)(o + a * D_ + d0 + 4 * i) = s;
    }
}

// ---------------------------------------------------------------------------
// proj: one block per 32 x-rows computes ALL 3 projections (x staged once).
// grid (M/32), block 384 = 6 waves: wave = (w = wid>>1, mt = wid&1).
// Each wave: 16 rows x 64 cols, 32 MFMA. Wave-local epilogue via LDS.
// q/k fp16 [M][64]; v fp16 TRANSPOSED [B][64][L].
// ---------------------------------------------------------------------------
__global__ __launch_bounds__(384) void proj_kernel(
    const float* __restrict__ x,           // [M][256] f32
    const unsigned short* __restrict__ wt, // [3][64][256] fp16 (W^T)
    unsigned short* __restrict__ qo,
    unsigned short* __restrict__ ko,
    unsigned short* __restrict__ vto)
{
    __shared__ __align__(16) unsigned short Xh[32 * 264];   // 16.5 KB
    __shared__ __align__(16) unsigned short Cst[6 * 1536];  // 18 KB
    const int t = threadIdx.x, m0 = blockIdx.x * 32;

    // stage x tile 32x256 -> fp16 (2048 float4 over 384 threads)
    #pragma unroll
    for (int p = 0; p < 6; ++p) {
        int idx = p * 384 + t;
        if (idx < 2048) {
            int row = idx >> 6, col = (idx & 63) * 4;
            float4 v = *(const float4*)(x + (size_t)(m0 + row) * D_ + col);
            ushort4 s;
            s.x = f2h_(v.x); s.y = f2h_(v.y); s.z = f2h_(v.z); s.w = f2h_(v.w);
            *(ushort4*)(Xh + row * 264 + col) = s;
        }
    }
    __syncthreads();

    const int wid = t >> 6, lane = t & 63, c = lane & 15, g = lane >> 4;
    const int w = wid >> 1, mt = wid & 1;

    half8 xa[8];
    #pragma unroll
    for (int s = 0; s < 8; ++s)
        xa[s] = *(const half8*)(Xh + (16 * mt + c) * 264 + 32 * s + 8 * g);

    const unsigned short* wsrc = wt + w * A_ * D_;
    unsigned short* Cw = Cst + wid * 1536;
    #pragma unroll
    for (int nt = 0; nt < 4; ++nt) {
        floatx4 acc = {0.f, 0.f, 0.f, 0.f};
        #pragma unroll
        for (int s = 0; s < 8; ++s) {
            half8 wb = *(const half8*)(wsrc + (16 * nt + c) * D_ + 32 * s + 8 * g);
            acc = __builtin_amdgcn_mfma_f32_16x16x32_f16(xa[s], wb, acc, 0, 0, 0);
        }
        // C[m=4g+r][a=16nt+c]
        if (w < 2) {
            #pragma unroll
            for (int r = 0; r < 4; ++r)
                Cw[(4 * g + r) * 72 + 16 * nt + c] = f2h_(acc[r]);      // [m16][72]
        } else {
            #pragma unroll
            for (int r = 0; r < 4; ++r)
                Cw[(16 * nt + c) * 24 + 4 * g + r] = f2h_(acc[r]);      // [a64][24]
        }
    }

    // q/k: wave-local store (wave reads only its own Cst region)
    if (w < 2) {
        unsigned short* o = (w == 0) ? qo : ko;
        const int row16 = lane >> 2, seg = lane & 3;
        uint4 d0 = *(const uint4*)(Cw + row16 * 72 + seg * 16);
        uint4 d1 = *(const uint4*)(Cw + row16 * 72 + seg * 16 + 8);
        unsigned short* p = o + (size_t)(m0 + 16 * mt + row16) * A_ + seg * 16;
        *(uint4*)(p) = d0;
        *(uint4*)(p + 8) = d1;
    }
    __syncthreads();
    // v: combined store from both w=2 waves -> 64B contiguous per a-row
    if (t < 256) {
        const int a = t >> 2, quarter = t & 3;
        const int o = quarter * 8, mtv = o >> 4, idx = o & 15;
        uint4 d = *(const uint4*)(Cst + (4 + mtv) * 1536 + a * 24 + idx);
        const int bb = m0 >> 12, l0 = m0 & (L_ - 1);
        *(uint4*)(vto + ((size_t)(bb * A_ + a)) * L_ + l0 + o) = d;
    }
}

// ---------------------------------------------------------------------------
// attn: split-K flash, 64-query blocks, 4-way key split. grid (1024) 1D,
// block 512 = 8 waves. 1024 blocks = exactly 4/CU resident (32 waves/CU cap,
// 4 x 36 KB = 144 <= 160 KB LDS) -> cross-block TLP hides the per-iteration
// stage->barrier latency that bound the split-2 version.
// Balanced mapping: slot = bx&255 -> same CU each of the 4 dispatch rounds;
// rounds 0,1 give (qt0, h=0/1), rounds 2,3 give (63-qt0, h=2/3), so per-CU
// key-tile totals are constant (~32.5 since T(q)+T(63-q) = 65). Max serial
// chain per block: ceil(64/4)/2 = 8 iterations (was 16).
// Wave = (qsub = wid>>1 in 0..3, ph = wid&1): 16 q-rows x one 64-key tile.
// S^T form: QK^T A=K,B=Q -> S^T[key][q=c]; softmax per-lane q row (exp2);
// PV: A=V^T 8B LDS frags, B=P^T in registers (K=16 chain).
// Emits UNNORMALIZED partial (O,m,l): h=0 -> out, h=1..3 -> po1..3/ml1..3.
// ---------------------------------------------------------------------------
__global__ __launch_bounds__(512) void attn_kernel(
    const unsigned short* __restrict__ qb,  // [B][L][64] fp16 (x 1/ln2)
    const unsigned short* __restrict__ kb,  // [B][L][64] fp16
    const unsigned short* __restrict__ vt,  // [B][64][L] fp16
    float* __restrict__ out,                // partial O for h=0
    float* __restrict__ po1,                // partial O for h=1
    float* __restrict__ po2,                // partial O for h=2
    float* __restrict__ po3,                // partial O for h=3
    float2* __restrict__ ml0,               // (m,l) h=0  [B*L]
    float2* __restrict__ ml1,
    float2* __restrict__ ml2,
    float2* __restrict__ ml3)
{
    __shared__ __align__(16) unsigned short smem[4 * 4608];  // 36 KB
    unsigned short* Ks = smem;
    unsigned short* Vs = smem + 2 * 4608;

    const int t    = threadIdx.x;
    const int lane = t & 63;
    const int wid  = t >> 6;          // 0..7
    const int qsub = wid >> 1;        // 0..3
    const int ph   = wid & 1;
    const int c    = lane & 15;
    const int g    = lane >> 4;

    // balanced (b, qt, h) from 1D block id
    const int bx   = blockIdx.x;
    const int slot = bx & 255, rr = bx >> 8;   // rr in 0..3 (dispatch round)
    const int qt0  = slot >> 2;
    const int b    = slot & 3;
    const int h    = rr;
    const int qt   = (rr < 2) ? qt0 : (63 - qt0);

    const int q0    = qt * 64;
    const int qrow0 = q0 + 16 * qsub;
    const int qme   = qrow0 + c;

    const size_t base  = (size_t)b * L_ * A_;
    const size_t vbase = (size_t)b * A_ * L_;

    half8 qf[2];
    {
        const unsigned short* qp = qb + base + (size_t)(qrow0 + c) * A_ + g * 8;
        qf[0] = *(const half8*)(qp);
        qf[1] = *(const half8*)(qp + 32);
    }

    floatx4 O4[4];          // O^T[a=16at+4g+r][q=c], unnormalized
    #pragma unroll
    for (int at = 0; at < 4; ++at) O4[at] = (floatx4){0.f, 0.f, 0.f, 0.f};
    float m_ = -INFINITY, l_ = 0.f;

    const int T   = qt + 1;           // 64-key tiles covering [0, q0+64)
    const int t0  = (h * T) >> 2;     // 4-way contiguous range split
    const int t1  = ((h + 1) * T) >> 2;
    const int nIt = (t1 - t0 + 1) >> 1;
    const int Tm1 = T - 1;

    for (int it = 0; it < nIt; ++it) {
        __syncthreads();
        #pragma unroll
        for (int tile = 0; tile < 2; ++tile) {
            const int kts = t0 + 2 * it + tile;
            if (kts < t1) {
                const int k0s = kts << 6;
                const int row = t >> 3, c8 = t & 7;   // 512 threads cover tile
                uint4 dK = *(const uint4*)(kb + base + (size_t)k0s * 64 + t * 8);
                *(uint4*)(Ks + tile * 4608 + row * 72 + c8 * 8) = dK;
                uint4 dV = *(const uint4*)(vt + vbase + (size_t)row * L_ + k0s + c8 * 8);
                *(uint4*)(Vs + tile * 4608 + row * 72 + c8 * 8) = dV;
            }
        }
        __syncthreads();

        const int kt = t0 + 2 * it + ph;
        if (kt >= t1) continue;          // loop-top barriers stay convergent
        const int k0 = kt << 6;
        const unsigned short* Kw = Ks + ph * 4608;
        const unsigned short* Vw = Vs + ph * 4608;

        // ---- S^T = K . Q^T ----
        floatx4 S4[4];
        #pragma unroll
        for (int nt = 0; nt < 4; ++nt) S4[nt] = (floatx4){0.f, 0.f, 0.f, 0.f};
        #pragma unroll
        for (int s = 0; s < 2; ++s)
            #pragma unroll
            for (int nt = 0; nt < 4; ++nt) {
                half8 kf = *(const half8*)(Kw + (16 * nt + c) * 72 + 32 * s + 8 * g);
                S4[nt] = __builtin_amdgcn_mfma_f32_16x16x32_f16(kf, qf[s], S4[nt], 0, 0, 0);
            }

        // ---- causal mask: only global tile T-1 straddles the diagonal ----
        if (kt == Tm1) {
            #pragma unroll
            for (int nt = 0; nt < 4; ++nt)
                #pragma unroll
                for (int r = 0; r < 4; ++r)
                    if (k0 + 16 * nt + 4 * g + r > qme) S4[nt][r] = -INFINITY;
        }

        // ---- online softmax (exp2 domain; per-lane q row) ----
        float tm = fmaxf(fmaxf(fmaxf(S4[0][0], S4[0][1]), fmaxf(S4[0][2], S4[0][3])),
                         fmaxf(fmaxf(S4[1][0], S4[1][1]), fmaxf(S4[1][2], S4[1][3])));
        tm = fmaxf(tm, fmaxf(fmaxf(fmaxf(S4[2][0], S4[2][1]), fmaxf(S4[2][2], S4[2][3])),
                             fmaxf(fmaxf(S4[3][0], S4[3][1]), fmaxf(S4[3][2], S4[3][3]))));
        tm = fmaxf(tm, __shfl_xor(tm, 16));
        tm = fmaxf(tm, __shfl_xor(tm, 32));
        const float mn  = fmaxf(m_, tm);
        const float mnc = fmaxf(mn, -3.0e38f);         // guard -inf - -inf
        const float al  = exp2f(fminf(m_ - mnc, 0.f)); // m_=-inf -> 0
        float rs = 0.f;
        half4 pf[4];
        #pragma unroll
        for (int nt = 0; nt < 4; ++nt) {
            #pragma unroll
            for (int r = 0; r < 4; ++r) {
                float p = exp2f(S4[nt][r] - mnc);      // masked: exp2(-inf)=0
                S4[nt][r] = p;
                rs += p;
            }
            pf[nt][0] = (_Float16)S4[nt][0];
            pf[nt][1] = (_Float16)S4[nt][1];
            pf[nt][2] = (_Float16)S4[nt][2];
            pf[nt][3] = (_Float16)S4[nt][3];
        }
        rs += __shfl_xor(rs, 16);
        rs += __shfl_xor(rs, 32);
        l_ = l_ * al + rs;
        m_ = mn;

        // ---- O^T = O^T*al + V^T . P^T  (V A-frags: 8B LDS reads) ----
        #pragma unroll
        for (int at = 0; at < 4; ++at) {
            O4[at] *= al;
            #pragma unroll
            for (int nt = 0; nt < 4; ++nt) {
                half4 va = *(const half4*)(Vw + (16 * at + c) * 72 + 16 * nt + 4 * g);
                O4[at] = __builtin_amdgcn_mfma_f32_16x16x16f16(va, pf[nt], O4[at], 0, 0, 0);
            }
        }
    }

    // ---- combine 2 phases per qsub; write unnormalized partial ----
    __syncthreads();
    float*  Of  = (float*)smem;                 // [wid][at][lane][r]  32 KB
    float2* mlb = (float2*)(smem + 16384);      // [wid][c]  (byte off 32768)
    #pragma unroll
    for (int at = 0; at < 4; ++at) {
        float4 v; v.x = O4[at][0]; v.y = O4[at][1]; v.z = O4[at][2]; v.w = O4[at][3];
        ((float4*)Of)[wid * 256 + at * 64 + lane] = v;
    }
    if (g == 0) { float2 ml; ml.x = m_; ml.y = l_; mlb[wid * 16 + c] = ml; }
    __syncthreads();

    {
        const int q64 = t >> 3, seg = t & 7;    // 64 q-rows x 8 segs
        const int qs = q64 >> 4, cc = q64 & 15;
        const float2 A0 = mlb[(2 * qs) * 16 + cc];
        const float2 A1 = mlb[(2 * qs + 1) * 16 + cc];
        const float mf = fmaxf(A0.x, A1.x);
        const float mc = fmaxf(mf, -3.0e38f);
        const float w0 = exp2f(A0.x - mc);      // -inf -> 0
        const float w1 = exp2f(A1.x - mc);
        const float ls = w0 * A0.y + w1 * A1.y;
        float res[8];
        #pragma unroll
        for (int u = 0; u < 8; ++u) {
            const int a = seg * 8 + u;
            const int at = a >> 4, gg = (a >> 2) & 3, r = a & 3;
            const int i0 = ((2 * qs) * 256 + at * 64 + gg * 16 + cc) * 4 + r;
            const int i1 = ((2 * qs + 1) * 256 + at * 64 + gg * 16 + cc) * 4 + r;
            res[u] = w0 * Of[i0] + w1 * Of[i1];
        }
        float* PO = (h == 0) ? out : (h == 1) ? po1 : (h == 2) ? po2 : po3;
        float* p = PO + (base + (size_t)(q0 + q64) * A_) + seg * 8;
        *(float4*)(p)     = make_float4(res[0], res[1], res[2], res[3]);
        *(float4*)(p + 4) = make_float4(res[4], res[5], res[6], res[7]);
        if (seg == 0) {
            float2 ml; ml.x = mf; ml.y = ls;
            float2* MLp = (h == 0) ? ml0 : (h == 1) ? ml1 : (h == 2) ? ml2 : ml3;
            MLp[b * L_ + q0 + q64] = ml;
        }
    }
}

// ---------------------------------------------------------------------------
// merge: final = sum(Oi*wi) / sum(li*wi) over 4 partials. grid (1024), block 256.
// ---------------------------------------------------------------------------
__global__ __launch_bounds__(256) void merge_kernel(
    float* __restrict__ out, const float* __restrict__ po1,
    const float* __restrict__ po2, const float* __restrict__ po3,
    const float2* __restrict__ ml0, const float2* __restrict__ ml1,
    const float2* __restrict__ ml2, const float2* __restrict__ ml3)
{
    const int tg = blockIdx.x * 256 + threadIdx.x;   // 262144 float4s
    const int q = tg >> 4;
    const float2 a0 = ml0[q], a1 = ml1[q], a2 = ml2[q], a3 = ml3[q];
    const float mf = fmaxf(fmaxf(a0.x, a1.x), fmaxf(a2.x, a3.x));
    const float mc = fmaxf(mf, -3.0e38f);
    const float w0 = exp2f(a0.x - mc);
    const float w1 = exp2f(a1.x - mc);
    const float w2 = exp2f(a2.x - mc);
    const float w3 = exp2f(a3.x - mc);
    const float inv = 1.f / (w0 * a0.y + w1 * a1.y + w2 * a2.y + w3 * a3.y);
    float4 o0 = ((const float4*)out)[tg];
    float4 o1 = ((const float4*)po1)[tg];
    float4 o2 = ((const float4*)po2)[tg];
    float4 o3 = ((const float4*)po3)[tg];
    float4 r;
    r.x = (o0.x * w0 + o1.x * w1 + o2.x * w2 + o3.x * w3) * inv;
    r.y = (o0.y * w0 + o1.y * w1 + o2.y * w2 + o3.y * w3) * inv;
    r.z = (o0.z * w0 + o1.z * w1 + o2.z * w2 + o3.z * w3) * inv;
    r.w = (o0.w * w0 + o1.w * w1 + o2.w * w2 + o3.w * w3) * inv;
    ((float4*)out)[tg] = r;
}

// ---------------------------------------------------------------------------
extern "C" void kernel_launch(void* const* d_in, const int* in_sizes, int n_in,
                              void* d_out, int out_size, void* d_ws, size_t ws_size,
                              hipStream_t stream) {
    const float* x  = (const float*)d_in[0];
    const float* Wq = (const float*)d_in[1];
    const float* Wk = (const float*)d_in[2];
    const float* Wv = (const float*)d_in[3];

    char* ws = (char*)d_ws;
    unsigned short* qb = (unsigned short*)(ws);                    // 2 MB
    unsigned short* kb = (unsigned short*)(ws + (2u << 20));       // 2 MB
    unsigned short* vt = (unsigned short*)(ws + (4u << 20));       // 2 MB
    unsigned short* wt = (unsigned short*)(ws + (6u << 20));       // 96 KB (128 KB reserved)
    char* p0 = ws + (6u << 20) + (128u << 10);
    float* po1 = (float*)(p0);                                     // 4 MB
    float* po2 = (float*)(p0 + (4u << 20));                        // 4 MB
    float* po3 = (float*)(p0 + (8u << 20));                        // 4 MB
    char* p1 = p0 + (12u << 20);
    float2* ml0 = (float2*)(p1);                                   // 128 KB
    float2* ml1 = (float2*)(p1 + (128u << 10));                    // 128 KB
    float2* ml2 = (float2*)(p1 + (256u << 10));                    // 128 KB
    float2* ml3 = (float2*)(p1 + (384u << 10));                    // 128 KB
    float* out = (float*)d_out;

    hipLaunchKernelGGL(wconv_kernel, dim3(3), dim3(256), 0, stream, Wq, Wk, Wv, wt);
    hipLaunchKernelGGL(proj_kernel, dim3(M_ / 32), dim3(384), 0, stream, x, wt, qb, kb, vt);
    hipLaunchKernelGGL(attn_kernel, dim3(1024), dim3(512), 0, stream,
                       qb, kb, vt, out, po1, po2, po3, ml0, ml1, ml2, ml3);
    hipLaunchKernelGGL(merge_kernel, dim3(1024), dim3(256), 0, stream,
                       out, po1, po2, po3, ml0, ml1, ml2, ml3);
}